// Round 5
// baseline (241.680 us; speedup 1.0000x reference)
//
#include <hip/hip_runtime.h>
#include <math.h>

#define NROWS 16384
#define DDIM  2048
#define EEXP  64
#define RB    32                 // rows per block -> grid 512
#define KC    64                 // k-columns per chunk
#define NCH   (DDIM / KC)        // 32 chunks

// d_ws layout: W pre-split into 3 bf16 levels, fragment-ordered.
// frag addr = ((((c*4 + kg)*2 + et)*64 + lane)*48) + lvl*16
#define WSPLIT_BYTES 786432
#define CHSTRIDE     24576       // 4 kg * 2 et * 64 lanes * 48 B

typedef short        bf16x8 __attribute__((ext_vector_type(8)));
typedef float        f32x16 __attribute__((ext_vector_type(16)));
typedef float        f32x4  __attribute__((ext_vector_type(4)));
typedef unsigned int u32x4  __attribute__((ext_vector_type(4)));

union V4 { u32x4 u; bf16x8 s; };

// Truncating 3-way bf16 split: f = X0 + X1 + X2 + eps, |eps| <= 2^-24 |f|
static __device__ __forceinline__ void split3x2(float f0, float f1,
                                                unsigned int &p0, unsigned int &p1,
                                                unsigned int &p2) {
    unsigned int a0 = __float_as_uint(f0), b0 = __float_as_uint(f1);
    unsigned int ah = a0 & 0xffff0000u,   bh = b0 & 0xffff0000u;
    float fa1 = f0 - __uint_as_float(ah);
    float fb1 = f1 - __uint_as_float(bh);
    unsigned int a1 = __float_as_uint(fa1), b1 = __float_as_uint(fb1);
    unsigned int am = a1 & 0xffff0000u,     bm = b1 & 0xffff0000u;
    float fa2 = fa1 - __uint_as_float(am);
    float fb2 = fb1 - __uint_as_float(bm);
    p0 = (a0 >> 16) | bh;
    p1 = (a1 >> 16) | bm;
    p2 = (__float_as_uint(fa2) >> 16) | (__float_as_uint(fb2) & 0xffff0000u);
}

static __device__ __forceinline__ void cvt8(f32x4 u, f32x4 v, V4 &q0, V4 &q1, V4 &q2) {
    unsigned int a, b, c;
    split3x2(u[0], u[1], a, b, c); q0.u[0] = a; q1.u[0] = b; q2.u[0] = c;
    split3x2(u[2], u[3], a, b, c); q0.u[1] = a; q1.u[1] = b; q2.u[1] = c;
    split3x2(v[0], v[1], a, b, c); q0.u[2] = a; q1.u[2] = b; q2.u[2] = c;
    split3x2(v[2], v[3], a, b, c); q0.u[3] = a; q1.u[3] = b; q2.u[3] = c;
}

#define MM(ACC, A, B) ACC = __builtin_amdgcn_mfma_f32_32x32x16_bf16((A), (B), ACC, 0, 0, 0)

#define STR_(x) #x
// saddr-form global load: 32-bit per-lane voffset + uniform SGPR base, literal imm
#define GLD(dst, voff, base, IMM)                                             \
    asm volatile("global_load_dwordx4 %0, %1, %2 offset:" STR_(IMM)           \
                 : "=v"(dst) : "v"(voff), "s"(base))
// counted wait + scheduler fence (rule #18)
#define WAITV(N)                                                              \
    asm volatile("s_waitcnt vmcnt(" STR_(N) ")" ::: "memory");                \
    __builtin_amdgcn_sched_barrier(0)

// consume one chunk: 3-level A split, 6 significant products on 2 acc chains
#define CONSUME(XA, XB, B0, B1, B2) {                                         \
    V4 a0, a1, a2; cvt8(XA, XB, a0, a1, a2);                                  \
    MM(accA, a0.s, B0.s); MM(accB, a0.s, B1.s); MM(accA, a1.s, B0.s);         \
    MM(accB, a0.s, B2.s); MM(accA, a1.s, B1.s); MM(accB, a2.s, B0.s); }

// issue one chunk-slot: 2 x-loads (slot-fixed imm) + 3 B-loads (+CHSTRIDE step)
#define ISSUE(XA, XB, B0, B1, B2, IMM0, IMM1)                                 \
    GLD(XA, voffx, x, IMM0); GLD(XB, voffx, x, IMM1);                         \
    GLD(B0.u, voffB, wsplit, 0); GLD(B1.u, voffB, wsplit, 16);                \
    GLD(B2.u, voffB, wsplit, 32); voffB += CHSTRIDE;

#define STEP(N, XA, XB, B0, B1, B2, IMM0, IMM1)                               \
    WAITV(N); CONSUME(XA, XB, B0, B1, B2) ISSUE(XA, XB, B0, B1, B2, IMM0, IMM1)

#define DRAIN(N, XA, XB, B0, B1, B2)                                          \
    WAITV(N); CONSUME(XA, XB, B0, B1, B2)

// ---- prep: W [2048][64] fp32 -> fragment-ordered 3-level bf16 split ----
__global__ __launch_bounds__(256)
void wsplit_kernel(const float* __restrict__ W, unsigned char* __restrict__ ws) {
    const int t  = blockIdx.x * 256 + threadIdx.x;
    const int e  = t & 63;
    const int ko = t >> 6;
    const int k0 = ko * 8;
    f32x4 u, v;
#pragma unroll
    for (int j = 0; j < 4; ++j) u[j] = W[(size_t)(k0 + j) * EEXP + e];
#pragma unroll
    for (int j = 0; j < 4; ++j) v[j] = W[(size_t)(k0 + 4 + j) * EEXP + e];
    V4 q0, q1, q2;
    cvt8(u, v, q0, q1, q2);
    const int c  = k0 >> 6;
    const int kg = (k0 >> 4) & 3;
    const int h  = (k0 >> 3) & 1;
    const int et = e >> 5;
    const int ln = h * 32 + (e & 31);
    unsigned char* d = ws + (size_t)(((((c * 4 + kg) * 2 + et) * 64) + ln) * 48);
    *(u32x4*)(d +  0) = q0.u;
    *(u32x4*)(d + 16) = q1.u;
    *(u32x4*)(d + 32) = q2.u;
}

__global__ __launch_bounds__(512, 2)     // VGPR cap 256: pinned pipeline must not spill
void router_kernel(const float* __restrict__ x,
                   const unsigned char* __restrict__ wsplit,
                   const float* __restrict__ bias_v,
                   float* __restrict__ mask_out,
                   float* __restrict__ idx_out) {
    __shared__ __align__(16) float ep[8192];   // 32 KB, epilogue only

    const int tid  = threadIdx.x;
    const int lane = tid & 63;
    const int w    = __builtin_amdgcn_readfirstlane(tid >> 6);
    const int kg   = w & 3;
    const int et   = w >> 2;
    const int row0 = blockIdx.x * RB;
    const int l31  = lane & 31;
    const int h    = lane >> 5;

    // per-lane 32-bit voffsets (saddr form); formulas identical to passing round 3
    unsigned int voffx = (unsigned int)(((row0 + l31) * DDIM + kg * 16 + h * 8) * 4);
    unsigned int voffB = (unsigned int)(((kg * 2 + et) * 64 + lane) * 48);

    f32x16 accA, accB;
#pragma unroll
    for (int i = 0; i < 16; ++i) { accA[i] = 0.f; accB[i] = 0.f; }

    // 8-deep pipeline slots, asm-pinned (192 VGPR + acc 32; cap 256 -> no spill)
    f32x4 X0a, X0b, X1a, X1b, X2a, X2b, X3a, X3b;
    f32x4 X4a, X4b, X5a, X5b, X6a, X6b, X7a, X7b;
    V4 B00, B01, B02, B10, B11, B12, B20, B21, B22, B30, B31, B32;
    V4 B40, B41, B42, B50, B51, B52, B60, B61, B62, B70, B71, B72;

    // ---- prologue: issue chunks 0..7 (40 loads in flight) ----
    ISSUE(X0a, X0b, B00, B01, B02,    0,   16)
    ISSUE(X1a, X1b, B10, B11, B12,  256,  272)
    ISSUE(X2a, X2b, B20, B21, B22,  512,  528)
    ISSUE(X3a, X3b, B30, B31, B32,  768,  784)
    ISSUE(X4a, X4b, B40, B41, B42, 1024, 1040)
    ISSUE(X5a, X5b, B50, B51, B52, 1280, 1296)
    ISSUE(X6a, X6b, B60, B61, B62, 1536, 1552)
    ISSUE(X7a, X7b, B70, B71, B72, 1792, 1808)
    voffx += 2048;

    // ---- steady state: 3 bodies x 8 chunks; wait vmcnt(35) = oldest slot done ----
#pragma unroll 1
    for (int j = 0; j < 3; ++j) {
        STEP(35, X0a, X0b, B00, B01, B02,    0,   16)
        STEP(35, X1a, X1b, B10, B11, B12,  256,  272)
        STEP(35, X2a, X2b, B20, B21, B22,  512,  528)
        STEP(35, X3a, X3b, B30, B31, B32,  768,  784)
        STEP(35, X4a, X4b, B40, B41, B42, 1024, 1040)
        STEP(35, X5a, X5b, B50, B51, B52, 1280, 1296)
        STEP(35, X6a, X6b, B60, B61, B62, 1536, 1552)
        STEP(35, X7a, X7b, B70, B71, B72, 1792, 1808)
        voffx += 2048;
    }

    // ---- drain: chunks 24..31, waits descend 35 -> 0 ----
    DRAIN(35, X0a, X0b, B00, B01, B02)
    DRAIN(30, X1a, X1b, B10, B11, B12)
    DRAIN(25, X2a, X2b, B20, B21, B22)
    DRAIN(20, X3a, X3b, B30, B31, B32)
    DRAIN(15, X4a, X4b, B40, B41, B42)
    DRAIN(10, X5a, X5b, B50, B51, B52)
    DRAIN(5,  X6a, X6b, B60, B61, B62)
    DRAIN(0,  X7a, X7b, B70, B71, B72)

    // ---- epilogue: reduce 4 kg-partials in LDS, softmax + top2 (round-3-identical) ----
    // C/D layout: col = lane&31, row = (reg&3) + 8*(reg>>2) + 4*(lane>>5)
#pragma unroll
    for (int r = 0; r < 16; ++r) {
        const int rowl = (r & 3) + 8 * (r >> 2) + 4 * h;
        ep[kg * 2048 + rowl * 64 + et * 32 + l31] = accA[r] + accB[r];
    }
    __syncthreads();

    const float bias = bias_v[lane];
#pragma unroll
    for (int rr = 0; rr < 4; ++rr) {
        const int rl  = w * 4 + rr;
        const int row = row0 + rl;
        float logit = bias + ep[rl * 64 + lane]
                           + ep[2048 + rl * 64 + lane]
                           + ep[4096 + rl * 64 + lane]
                           + ep[6144 + rl * 64 + lane];

        float m = logit;
#pragma unroll
        for (int off = 32; off >= 1; off >>= 1) m = fmaxf(m, __shfl_xor(m, off));
        float ex = __expf(logit - m);
        float s = ex;
#pragma unroll
        for (int off = 32; off >= 1; off >>= 1) s += __shfl_xor(s, off);
        float gate = ex / s;

        float v1 = logit; int i1 = lane;
#pragma unroll
        for (int off = 32; off >= 1; off >>= 1) {
            float ov = __shfl_xor(v1, off);
            int   oi = __shfl_xor(i1, off);
            if (ov > v1 || (ov == v1 && oi < i1)) { v1 = ov; i1 = oi; }
        }
        float v2 = (lane == i1) ? -INFINITY : logit; int i2 = lane;
#pragma unroll
        for (int off = 32; off >= 1; off >>= 1) {
            float ov = __shfl_xor(v2, off);
            int   oi = __shfl_xor(i2, off);
            if (ov > v2 || (ov == v2 && oi < i2)) { v2 = ov; i2 = oi; }
        }

        float outv = (lane == i1 || lane == i2) ? gate : 0.0f;
        mask_out[(size_t)row * EEXP + lane] = outv;
        if (lane == 0) {
            idx_out[row * 2 + 0] = (float)i1;
            idx_out[row * 2 + 1] = (float)i2;
        }
    }
}

extern "C" void kernel_launch(void* const* d_in, const int* in_sizes, int n_in,
                              void* d_out, int out_size, void* d_ws, size_t ws_size,
                              hipStream_t stream) {
    const float* x = (const float*)d_in[0];
    const float* W = (const float*)d_in[1];
    const float* b = (const float*)d_in[2];
    float* mask_out = (float*)d_out;
    float* idx_out  = mask_out + (size_t)NROWS * EEXP;
    unsigned char* ws = (unsigned char*)d_ws;   // needs 768 KB

    wsplit_kernel<<<dim3(64), dim3(256), 0, stream>>>(W, ws);
    router_kernel<<<dim3(NROWS / RB), dim3(512), 0, stream>>>(x, ws, b, mask_out, idx_out);
}

// Round 6
// 212.293 us; speedup vs baseline: 1.1384x; 1.1384x over previous
//
#include <hip/hip_runtime.h>
#include <math.h>

#define NROWS 16384
#define DDIM  2048
#define EEXP  64
#define RB    32                 // rows per block -> grid 512
#define NST   8                  // stage-steps, 256 floats of k each
#define CHSTRIDE 24576           // wsplit: 4 kg * 2 et * 64 lanes * 48 B per chunk

typedef short        bf16x8 __attribute__((ext_vector_type(8)));
typedef float        f32x16 __attribute__((ext_vector_type(16)));
typedef float        f32x4  __attribute__((ext_vector_type(4)));
typedef unsigned int u32x4  __attribute__((ext_vector_type(4)));

union V4 { u32x4 u; bf16x8 s; };

// Truncating 3-way bf16 split: f = X0 + X1 + X2 + eps, |eps| <= 2^-24 |f|
static __device__ __forceinline__ void split3x2(float f0, float f1,
                                                unsigned int &p0, unsigned int &p1,
                                                unsigned int &p2) {
    unsigned int a0 = __float_as_uint(f0), b0 = __float_as_uint(f1);
    unsigned int ah = a0 & 0xffff0000u,   bh = b0 & 0xffff0000u;
    float fa1 = f0 - __uint_as_float(ah);
    float fb1 = f1 - __uint_as_float(bh);
    unsigned int a1 = __float_as_uint(fa1), b1 = __float_as_uint(fb1);
    unsigned int am = a1 & 0xffff0000u,     bm = b1 & 0xffff0000u;
    float fa2 = fa1 - __uint_as_float(am);
    float fb2 = fb1 - __uint_as_float(bm);
    p0 = (a0 >> 16) | bh;
    p1 = (a1 >> 16) | bm;
    p2 = (__float_as_uint(fa2) >> 16) | (__float_as_uint(fb2) & 0xffff0000u);
}

static __device__ __forceinline__ void cvt8(f32x4 u, f32x4 v, V4 &q0, V4 &q1, V4 &q2) {
    unsigned int a, b, c;
    split3x2(u[0], u[1], a, b, c); q0.u[0] = a; q1.u[0] = b; q2.u[0] = c;
    split3x2(u[2], u[3], a, b, c); q0.u[1] = a; q1.u[1] = b; q2.u[1] = c;
    split3x2(v[0], v[1], a, b, c); q0.u[2] = a; q1.u[2] = b; q2.u[2] = c;
    split3x2(v[2], v[3], a, b, c); q0.u[3] = a; q1.u[3] = b; q2.u[3] = c;
}

#define MM(ACC, A, B) ACC = __builtin_amdgcn_mfma_f32_32x32x16_bf16((A), (B), ACC, 0, 0, 0)

// ---- prep: W [2048][64] fp32 -> fragment-ordered 3-level bf16 split (as R5) ----
__global__ __launch_bounds__(256)
void wsplit_kernel(const float* __restrict__ W, unsigned char* __restrict__ ws) {
    const int t  = blockIdx.x * 256 + threadIdx.x;
    const int e  = t & 63;
    const int ko = t >> 6;
    const int k0 = ko * 8;
    f32x4 u, v;
#pragma unroll
    for (int j = 0; j < 4; ++j) u[j] = W[(size_t)(k0 + j) * EEXP + e];
#pragma unroll
    for (int j = 0; j < 4; ++j) v[j] = W[(size_t)(k0 + 4 + j) * EEXP + e];
    V4 q0, q1, q2;
    cvt8(u, v, q0, q1, q2);
    const int c  = k0 >> 6;
    const int kg = (k0 >> 4) & 3;
    const int h  = (k0 >> 3) & 1;
    const int et = e >> 5;
    const int ln = h * 32 + (e & 31);
    unsigned char* d = ws + (size_t)(((((c * 4 + kg) * 2 + et) * 64) + ln) * 48);
    *(u32x4*)(d +  0) = q0.u;
    *(u32x4*)(d + 16) = q1.u;
    *(u32x4*)(d + 32) = q2.u;
}

__global__ __launch_bounds__(512, 2)
void router_kernel(const float* __restrict__ x,
                   const unsigned char* __restrict__ wsplit,
                   const float* __restrict__ bias_v,
                   float* __restrict__ mask_out,
                   float* __restrict__ idx_out) {
    // x tile: [2 bufs][32 rows][256 floats] = 64 KB; epilogue (32 KB) overlays buf0
    __shared__ __align__(16) float smem[16384];

    const int tid  = threadIdx.x;
    const int lane = tid & 63;
    const int w    = __builtin_amdgcn_readfirstlane(tid >> 6);
    const int kg   = w & 3;
    const int et   = w >> 2;
    const int l31  = lane & 31;
    const int h    = lane >> 5;

    // XCD-aware bijective swizzle (512 % 8 == 0)
    const int bid  = blockIdx.x;
    const int bswz = (bid & 7) * ((int)gridDim.x >> 3) + (bid >> 3);
    const int row0 = bswz * RB;

    // staging: wave w owns rows 4w..4w+3; lane l reads 16 B at +l*16 -> 1 KB
    // contiguous per row per stage. LDS write swizzles 16 B block: blk = l ^ (row&7).
    const int srow = 4 * w;

    // B stream base (layout identical to round 5; c = s*4+cc)
    const unsigned char* wp = wsplit + (size_t)(((kg * 2 + et) * 64 + lane) * 48);

    f32x16 accA, accB;
#pragma unroll
    for (int i = 0; i < 16; ++i) { accA[i] = 0.f; accB[i] = 0.f; }

    // ---- prologue: stage 0 ----
    {
        f32x4 X0, X1, X2, X3;
        X0 = *(const f32x4*)(x + (size_t)(row0 + srow + 0) * DDIM + lane * 4);
        X1 = *(const f32x4*)(x + (size_t)(row0 + srow + 1) * DDIM + lane * 4);
        X2 = *(const f32x4*)(x + (size_t)(row0 + srow + 2) * DDIM + lane * 4);
        X3 = *(const f32x4*)(x + (size_t)(row0 + srow + 3) * DDIM + lane * 4);
#define XWR(I, V, B)                                                          \
        *(f32x4*)(smem + (B) * 8192 + (srow + I) * 256 +                      \
                  ((lane ^ ((srow + I) & 7)) << 2)) = V;
        XWR(0, X0, 0) XWR(1, X1, 0) XWR(2, X2, 0) XWR(3, X3, 0)
    }
    __syncthreads();

#pragma unroll 1
    for (int s = 0; s < NST; ++s) {
        const int  buf  = s & 1;
        const bool more = (s + 1) < NST;

        f32x4 X0, X1, X2, X3;
        if (more) {   // wave-contiguous 1 KB bursts for next stage
            const float* xs = x + (size_t)(s + 1) * 256 + lane * 4;
            X0 = *(const f32x4*)(xs + (size_t)(row0 + srow + 0) * DDIM);
            X1 = *(const f32x4*)(xs + (size_t)(row0 + srow + 1) * DDIM);
            X2 = *(const f32x4*)(xs + (size_t)(row0 + srow + 2) * DDIM);
            X3 = *(const f32x4*)(xs + (size_t)(row0 + srow + 3) * DDIM);
        }

        // consume 4 chunks (KC=64 each) of this stage from LDS
        const float* xb = smem + buf * 8192 + l31 * 256;
        const int xr = l31 & 7;
#pragma unroll
        for (int cc = 0; cc < 4; ++cc) {
            const int k0 = cc * 64 + kg * 16 + h * 8;
            const int bb = k0 >> 2;                    // even 16B-block index
            f32x4 lo = *(const f32x4*)(xb + (((bb    ) ^ xr) << 2));
            f32x4 hi = *(const f32x4*)(xb + (((bb + 1) ^ xr) << 2));
            const unsigned char* q = wp + (size_t)(s * 4 + cc) * CHSTRIDE;
            V4 b0, b1, b2;
            b0.u = *(const u32x4*)(q);
            b1.u = *(const u32x4*)(q + 16);
            b2.u = *(const u32x4*)(q + 32);
            V4 a0, a1, a2;
            cvt8(lo, hi, a0, a1, a2);
            MM(accA, a0.s, b0.s); MM(accB, a0.s, b1.s); MM(accA, a1.s, b0.s);
            MM(accB, a0.s, b2.s); MM(accA, a1.s, b1.s); MM(accB, a2.s, b0.s);
        }

        if (more) {   // write next stage into the other buffer
            const int nb = buf ^ 1;
            XWR(0, X0, nb) XWR(1, X1, nb) XWR(2, X2, nb) XWR(3, X3, nb)
        }
        __syncthreads();
    }

    // ---- epilogue: reduce 4 kg-partials in LDS, softmax + top2 (R5-identical) ----
    // C/D layout: col = lane&31, row = (reg&3) + 8*(reg>>2) + 4*(lane>>5)
    float* ep = smem;
#pragma unroll
    for (int r = 0; r < 16; ++r) {
        const int rowl = (r & 3) + 8 * (r >> 2) + 4 * h;
        ep[kg * 2048 + rowl * 64 + et * 32 + l31] = accA[r] + accB[r];
    }
    __syncthreads();

    const float bias = bias_v[lane];
#pragma unroll
    for (int rr = 0; rr < 4; ++rr) {
        const int rl  = w * 4 + rr;
        const int row = row0 + rl;
        float logit = bias + ep[rl * 64 + lane]
                           + ep[2048 + rl * 64 + lane]
                           + ep[4096 + rl * 64 + lane]
                           + ep[6144 + rl * 64 + lane];

        float m = logit;
#pragma unroll
        for (int off = 32; off >= 1; off >>= 1) m = fmaxf(m, __shfl_xor(m, off));
        float ex = __expf(logit - m);
        float s = ex;
#pragma unroll
        for (int off = 32; off >= 1; off >>= 1) s += __shfl_xor(s, off);
        float gate = ex / s;

        float v1 = logit; int i1 = lane;
#pragma unroll
        for (int off = 32; off >= 1; off >>= 1) {
            float ov = __shfl_xor(v1, off);
            int   oi = __shfl_xor(i1, off);
            if (ov > v1 || (ov == v1 && oi < i1)) { v1 = ov; i1 = oi; }
        }
        float v2 = (lane == i1) ? -INFINITY : logit; int i2 = lane;
#pragma unroll
        for (int off = 32; off >= 1; off >>= 1) {
            float ov = __shfl_xor(v2, off);
            int   oi = __shfl_xor(i2, off);
            if (ov > v2 || (ov == v2 && oi < i2)) { v2 = ov; i2 = oi; }
        }

        float outv = (lane == i1 || lane == i2) ? gate : 0.0f;
        mask_out[(size_t)row * EEXP + lane] = outv;
        if (lane == 0) {
            idx_out[row * 2 + 0] = (float)i1;
            idx_out[row * 2 + 1] = (float)i2;
        }
    }
}

extern "C" void kernel_launch(void* const* d_in, const int* in_sizes, int n_in,
                              void* d_out, int out_size, void* d_ws, size_t ws_size,
                              hipStream_t stream) {
    const float* x = (const float*)d_in[0];
    const float* W = (const float*)d_in[1];
    const float* b = (const float*)d_in[2];
    float* mask_out = (float*)d_out;
    float* idx_out  = mask_out + (size_t)NROWS * EEXP;
    unsigned char* ws = (unsigned char*)d_ws;   // needs 768 KB

    wsplit_kernel<<<dim3(64), dim3(256), 0, stream>>>(W, ws);
    router_kernel<<<dim3(NROWS / RB), dim3(512), 0, stream>>>(x, ws, b, mask_out, idx_out);
}